// Round 1
// baseline (1934.234 us; speedup 1.0000x reference)
//
#include <hip/hip_runtime.h>

// AttnBlock: B=32, C=512, H=W=32 -> N=1024 pixels, 32 groups GN, eps 1e-6.
// Pipeline: GN -> q/k/v (1x1 conv == GEMM) -> S=scale*q^T k -> softmax ->
//           O = P v -> proj + residual.
// fp32 in/out; intermediates h,q,k,v,O stored bf16 (fp32 math), attn fp32.

#define C_DIM 512
#define N_PIX 1024
#define BATCH 32
#define NGRP 32
#define CPG 16            // channels per group
#define EPS 1e-6f
#define SCALE 0.044194173824159216f  // 512^-0.5

typedef unsigned short u16;

static __device__ __forceinline__ float bf2f(u16 u) {
    union { unsigned int i; float f; } v; v.i = ((unsigned int)u) << 16; return v.f;
}
static __device__ __forceinline__ u16 f2bf(float f) {
    union { float f; unsigned int i; } v; v.f = f;
    unsigned int r = v.i + 0x7fffu + ((v.i >> 16) & 1u);   // round-nearest-even
    return (u16)(r >> 16);
}

// ---------------------------------------------------------------- GroupNorm
// grid: B*NGRP blocks, 256 threads. Each block: one (b,g): 16 ch x 1024 pix.
__global__ void gn_kernel(const float* __restrict__ x,
                          const float* __restrict__ gw,
                          const float* __restrict__ gb,
                          u16* __restrict__ h) {
    int blk = blockIdx.x;
    int b = blk >> 5, g = blk & 31;
    size_t base = ((size_t)(b * C_DIM + g * CPG)) * N_PIX;   // elems
    const float4* xv = (const float4*)(x + base);
    int tid = threadIdx.x;

    float s = 0.f, sq = 0.f;
    for (int i = tid; i < (CPG * N_PIX) / 4; i += 256) {     // 4096 float4
        float4 v = xv[i];
        s  += v.x + v.y + v.z + v.w;
        sq += v.x * v.x + v.y * v.y + v.z * v.z + v.w * v.w;
    }
    __shared__ float rs[256], rq[256];
    rs[tid] = s; rq[tid] = sq;
    __syncthreads();
    for (int off = 128; off > 0; off >>= 1) {
        if (tid < off) { rs[tid] += rs[tid + off]; rq[tid] += rq[tid + off]; }
        __syncthreads();
    }
    float mean = rs[0] * (1.0f / (CPG * N_PIX));
    float var  = rq[0] * (1.0f / (CPG * N_PIX)) - mean * mean;
    float inv  = rsqrtf(var + EPS);

    u16* hp = h + base;
    for (int i = tid; i < (CPG * N_PIX) / 4; i += 256) {
        int c_local = i >> 8;                  // (i*4)/1024
        int c = g * CPG + c_local;
        float sc = gw[c] * inv;
        float sh = gb[c] - mean * sc;
        float4 v = xv[i];
        ushort4 o;
        o.x = f2bf(v.x * sc + sh); o.y = f2bf(v.y * sc + sh);
        o.z = f2bf(v.z * sc + sh); o.w = f2bf(v.w * sc + sh);
        *(ushort4*)(hp + i * 4) = o;
    }
}

// ---------------------------------------------------------------- QKV GEMM
// out_m[b][o][n] = sum_c W_m[o][c] * h[b][c][n] + bias_m[o]   (bf16 out)
// grid: (nT=16, oT=8, mat*32+b=96), 256 thr, 64x64 tile, BK=16, 4x4 micro.
__global__ void qkv_kernel(const u16* __restrict__ h,
                           const float* __restrict__ wq, const float* __restrict__ wk,
                           const float* __restrict__ wv,
                           const float* __restrict__ bq, const float* __restrict__ bk,
                           const float* __restrict__ bv,
                           u16* __restrict__ q, u16* __restrict__ k, u16* __restrict__ v) {
    int nT = blockIdx.x, oT = blockIdx.y, mb = blockIdx.z;
    int mat = mb >> 5, b = mb & 31;
    const float* W    = (mat == 0) ? wq : (mat == 1) ? wk : wv;
    const float* bias = (mat == 0) ? bq : (mat == 1) ? bk : bv;
    u16* out          = (mat == 0) ? q  : (mat == 1) ? k  : v;

    __shared__ float As[16][68];   // [c][o]
    __shared__ float Bs[16][68];   // [c][n]
    int tid = threadIdx.x;
    int tx = tid & 15, ty = tid >> 4;
    int o0 = oT * 64, n0 = nT * 64;
    const u16* hb = h + (size_t)b * C_DIM * N_PIX;

    int ar = tid >> 2, acq = tid & 3;    // A stage: row o0+ar, 4 c's
    int bcc = tid >> 4, bcq = tid & 15;  // B stage: c0+bcc, 4 n's

    float acc[4][4] = {};
    for (int c0 = 0; c0 < C_DIM; c0 += 16) {
        float4 a4 = *(const float4*)&W[(size_t)(o0 + ar) * C_DIM + c0 + acq * 4];
        As[acq * 4 + 0][ar] = a4.x; As[acq * 4 + 1][ar] = a4.y;
        As[acq * 4 + 2][ar] = a4.z; As[acq * 4 + 3][ar] = a4.w;
        ushort4 hv = *(const ushort4*)&hb[(size_t)(c0 + bcc) * N_PIX + n0 + bcq * 4];
        *(float4*)&Bs[bcc][bcq * 4] =
            make_float4(bf2f(hv.x), bf2f(hv.y), bf2f(hv.z), bf2f(hv.w));
        __syncthreads();
#pragma unroll
        for (int kk = 0; kk < 16; kk++) {
            float4 a  = *(float4*)&As[kk][ty * 4];
            float4 bb = *(float4*)&Bs[kk][tx * 4];
            acc[0][0] += a.x * bb.x; acc[0][1] += a.x * bb.y; acc[0][2] += a.x * bb.z; acc[0][3] += a.x * bb.w;
            acc[1][0] += a.y * bb.x; acc[1][1] += a.y * bb.y; acc[1][2] += a.y * bb.z; acc[1][3] += a.y * bb.w;
            acc[2][0] += a.z * bb.x; acc[2][1] += a.z * bb.y; acc[2][2] += a.z * bb.z; acc[2][3] += a.z * bb.w;
            acc[3][0] += a.w * bb.x; acc[3][1] += a.w * bb.y; acc[3][2] += a.w * bb.z; acc[3][3] += a.w * bb.w;
        }
        __syncthreads();
    }
#pragma unroll
    for (int i = 0; i < 4; i++) {
        int o = o0 + ty * 4 + i;
        float bi = bias[o];
        ushort4 st;
        st.x = f2bf(acc[i][0] + bi); st.y = f2bf(acc[i][1] + bi);
        st.z = f2bf(acc[i][2] + bi); st.w = f2bf(acc[i][3] + bi);
        *(ushort4*)&out[((size_t)b * C_DIM + o) * N_PIX + n0 + tx * 4] = st;
    }
}

// ---------------------------------------------------------------- Scores
// attn[bl][i][j] = SCALE * sum_c q[b][c][i] * k[b][c][j]   (fp32 out, chunked)
// grid: (jT=16, iT=16, chunkB)
__global__ void scores_kernel(const u16* __restrict__ q, const u16* __restrict__ k,
                              float* __restrict__ attn, int b0) {
    int jT = blockIdx.x, iT = blockIdx.y, bl = blockIdx.z;
    int b = b0 + bl;
    __shared__ float As[16][68];   // [c][i]
    __shared__ float Bs[16][68];   // [c][j]
    int tid = threadIdx.x;
    int tx = tid & 15, ty = tid >> 4;
    int i0 = iT * 64, j0 = jT * 64;
    const u16* qb = q + (size_t)b * C_DIM * N_PIX;
    const u16* kb = k + (size_t)b * C_DIM * N_PIX;
    int cc = tid >> 4, cq = tid & 15;

    float acc[4][4] = {};
    for (int c0 = 0; c0 < C_DIM; c0 += 16) {
        ushort4 qv = *(const ushort4*)&qb[(size_t)(c0 + cc) * N_PIX + i0 + cq * 4];
        ushort4 kv = *(const ushort4*)&kb[(size_t)(c0 + cc) * N_PIX + j0 + cq * 4];
        *(float4*)&As[cc][cq * 4] = make_float4(bf2f(qv.x), bf2f(qv.y), bf2f(qv.z), bf2f(qv.w));
        *(float4*)&Bs[cc][cq * 4] = make_float4(bf2f(kv.x), bf2f(kv.y), bf2f(kv.z), bf2f(kv.w));
        __syncthreads();
#pragma unroll
        for (int kk = 0; kk < 16; kk++) {
            float4 a  = *(float4*)&As[kk][ty * 4];
            float4 bb = *(float4*)&Bs[kk][tx * 4];
            acc[0][0] += a.x * bb.x; acc[0][1] += a.x * bb.y; acc[0][2] += a.x * bb.z; acc[0][3] += a.x * bb.w;
            acc[1][0] += a.y * bb.x; acc[1][1] += a.y * bb.y; acc[1][2] += a.y * bb.z; acc[1][3] += a.y * bb.w;
            acc[2][0] += a.z * bb.x; acc[2][1] += a.z * bb.y; acc[2][2] += a.z * bb.z; acc[2][3] += a.z * bb.w;
            acc[3][0] += a.w * bb.x; acc[3][1] += a.w * bb.y; acc[3][2] += a.w * bb.z; acc[3][3] += a.w * bb.w;
        }
        __syncthreads();
    }
#pragma unroll
    for (int i = 0; i < 4; i++) {
        int ii = i0 + ty * 4 + i;
        float4 st = make_float4(acc[i][0] * SCALE, acc[i][1] * SCALE,
                                acc[i][2] * SCALE, acc[i][3] * SCALE);
        *(float4*)&attn[((size_t)bl * N_PIX + ii) * N_PIX + j0 + tx * 4] = st;
    }
}

// ---------------------------------------------------------------- Softmax
// in-place over rows of 1024. grid: chunkB*1024 blocks, 256 thr.
__global__ void softmax_kernel(float* __restrict__ attn) {
    size_t row = blockIdx.x;
    float* p = attn + row * N_PIX;
    int tid = threadIdx.x;
    float4 v = ((float4*)p)[tid];
    __shared__ float red[256];
    float m = fmaxf(fmaxf(v.x, v.y), fmaxf(v.z, v.w));
    red[tid] = m; __syncthreads();
    for (int off = 128; off > 0; off >>= 1) {
        if (tid < off) red[tid] = fmaxf(red[tid], red[tid + off]);
        __syncthreads();
    }
    float M = red[0];
    __syncthreads();
    float4 e;
    e.x = expf(v.x - M); e.y = expf(v.y - M); e.z = expf(v.z - M); e.w = expf(v.w - M);
    red[tid] = e.x + e.y + e.z + e.w; __syncthreads();
    for (int off = 128; off > 0; off >>= 1) {
        if (tid < off) red[tid] += red[tid + off];
        __syncthreads();
    }
    float inv = 1.0f / red[0];
    e.x *= inv; e.y *= inv; e.z *= inv; e.w *= inv;
    ((float4*)p)[tid] = e;
}

// ---------------------------------------------------------------- PV GEMM
// O[b][i][c] = sum_j P[bl][i][j] * v[b][c][j]   (bf16 out)
// grid: (cT=8, iT=16, chunkB). K = 1024 (j), both operands transposed on stage.
__global__ void pv_kernel(const float* __restrict__ attn, const u16* __restrict__ v,
                          u16* __restrict__ O, int b0) {
    int cT = blockIdx.x, iT = blockIdx.y, bl = blockIdx.z;
    int b = b0 + bl;
    __shared__ float As[16][68];   // [j][i]
    __shared__ float Bs[16][68];   // [j][c]
    int tid = threadIdx.x;
    int tx = tid & 15, ty = tid >> 4;
    int i0 = iT * 64, c0 = cT * 64;
    const float* Pb = attn + (size_t)bl * N_PIX * N_PIX;
    const u16* vb = v + (size_t)b * C_DIM * N_PIX;
    int r = tid >> 2, cq = tid & 3;

    float acc[4][4] = {};
    for (int j0 = 0; j0 < N_PIX; j0 += 16) {
        float4 p4 = *(const float4*)&Pb[(size_t)(i0 + r) * N_PIX + j0 + cq * 4];
        As[cq * 4 + 0][r] = p4.x; As[cq * 4 + 1][r] = p4.y;
        As[cq * 4 + 2][r] = p4.z; As[cq * 4 + 3][r] = p4.w;
        ushort4 v4 = *(const ushort4*)&vb[(size_t)(c0 + r) * N_PIX + j0 + cq * 4];
        Bs[cq * 4 + 0][r] = bf2f(v4.x); Bs[cq * 4 + 1][r] = bf2f(v4.y);
        Bs[cq * 4 + 2][r] = bf2f(v4.z); Bs[cq * 4 + 3][r] = bf2f(v4.w);
        __syncthreads();
#pragma unroll
        for (int kk = 0; kk < 16; kk++) {
            float4 a  = *(float4*)&As[kk][ty * 4];
            float4 bb = *(float4*)&Bs[kk][tx * 4];
            acc[0][0] += a.x * bb.x; acc[0][1] += a.x * bb.y; acc[0][2] += a.x * bb.z; acc[0][3] += a.x * bb.w;
            acc[1][0] += a.y * bb.x; acc[1][1] += a.y * bb.y; acc[1][2] += a.y * bb.z; acc[1][3] += a.y * bb.w;
            acc[2][0] += a.z * bb.x; acc[2][1] += a.z * bb.y; acc[2][2] += a.z * bb.z; acc[2][3] += a.z * bb.w;
            acc[3][0] += a.w * bb.x; acc[3][1] += a.w * bb.y; acc[3][2] += a.w * bb.z; acc[3][3] += a.w * bb.w;
        }
        __syncthreads();
    }
#pragma unroll
    for (int i = 0; i < 4; i++) {
        int ii = i0 + ty * 4 + i;
        ushort4 st;
        st.x = f2bf(acc[i][0]); st.y = f2bf(acc[i][1]);
        st.z = f2bf(acc[i][2]); st.w = f2bf(acc[i][3]);
        *(ushort4*)&O[((size_t)b * N_PIX + ii) * C_DIM + c0 + tx * 4] = st;
    }
}

// ---------------------------------------------------------------- Proj + res
// y[b][o][n] = x[b][o][n] + bp[o] + sum_c wp[o][c] * O[b][n][c]
// grid: (nT=16, oT=8, b=32)
__global__ void proj_kernel(const u16* __restrict__ O, const float* __restrict__ wp,
                            const float* __restrict__ bp, const float* __restrict__ x,
                            float* __restrict__ y) {
    int nT = blockIdx.x, oT = blockIdx.y, b = blockIdx.z;
    __shared__ float As[16][68];   // [c][o]
    __shared__ float Bs[16][68];   // [c][n]
    int tid = threadIdx.x;
    int tx = tid & 15, ty = tid >> 4;
    int o0 = oT * 64, n0 = nT * 64;
    const u16* Ob = O + (size_t)b * N_PIX * C_DIM;
    int r = tid >> 2, cq = tid & 3;

    float acc[4][4] = {};
    for (int c0 = 0; c0 < C_DIM; c0 += 16) {
        float4 w4 = *(const float4*)&wp[(size_t)(o0 + r) * C_DIM + c0 + cq * 4];
        As[cq * 4 + 0][r] = w4.x; As[cq * 4 + 1][r] = w4.y;
        As[cq * 4 + 2][r] = w4.z; As[cq * 4 + 3][r] = w4.w;
        ushort4 o4 = *(const ushort4*)&Ob[(size_t)(n0 + r) * C_DIM + c0 + cq * 4];
        Bs[cq * 4 + 0][r] = bf2f(o4.x); Bs[cq * 4 + 1][r] = bf2f(o4.y);
        Bs[cq * 4 + 2][r] = bf2f(o4.z); Bs[cq * 4 + 3][r] = bf2f(o4.w);
        __syncthreads();
#pragma unroll
        for (int kk = 0; kk < 16; kk++) {
            float4 a  = *(float4*)&As[kk][ty * 4];
            float4 bb = *(float4*)&Bs[kk][tx * 4];
            acc[0][0] += a.x * bb.x; acc[0][1] += a.x * bb.y; acc[0][2] += a.x * bb.z; acc[0][3] += a.x * bb.w;
            acc[1][0] += a.y * bb.x; acc[1][1] += a.y * bb.y; acc[1][2] += a.y * bb.z; acc[1][3] += a.y * bb.w;
            acc[2][0] += a.z * bb.x; acc[2][1] += a.z * bb.y; acc[2][2] += a.z * bb.z; acc[2][3] += a.z * bb.w;
            acc[3][0] += a.w * bb.x; acc[3][1] += a.w * bb.y; acc[3][2] += a.w * bb.z; acc[3][3] += a.w * bb.w;
        }
        __syncthreads();
    }
#pragma unroll
    for (int i = 0; i < 4; i++) {
        int o = o0 + ty * 4 + i;
        float bi = bp[o];
        size_t idx = ((size_t)b * C_DIM + o) * N_PIX + n0 + tx * 4;
        float4 xr = *(const float4*)&x[idx];
        float4 st = make_float4(xr.x + bi + acc[i][0], xr.y + bi + acc[i][1],
                                xr.z + bi + acc[i][2], xr.w + bi + acc[i][3]);
        *(float4*)&y[idx] = st;
    }
}

extern "C" void kernel_launch(void* const* d_in, const int* in_sizes, int n_in,
                              void* d_out, int out_size, void* d_ws, size_t ws_size,
                              hipStream_t stream) {
    const float* x    = (const float*)d_in[0];
    const float* gn_w = (const float*)d_in[1];
    const float* gn_b = (const float*)d_in[2];
    const float* wq   = (const float*)d_in[3];
    const float* bq   = (const float*)d_in[4];
    const float* wk   = (const float*)d_in[5];
    const float* bk   = (const float*)d_in[6];
    const float* wv   = (const float*)d_in[7];
    const float* bv   = (const float*)d_in[8];
    const float* wp   = (const float*)d_in[9];
    const float* bp   = (const float*)d_in[10];
    float* y = (float*)d_out;

    const size_t BCN = (size_t)BATCH * C_DIM * N_PIX;        // 16.78M elems
    char* w = (char*)d_ws;
    u16* h = (u16*)(w);
    u16* q = (u16*)(w + 2 * BCN);
    u16* k = (u16*)(w + 4 * BCN);
    u16* v = (u16*)(w + 6 * BCN);
    u16* O = (u16*)(w + 8 * BCN);
    float* attn = (float*)(w + 10 * BCN);                    // 160 MiB fixed
    long long rem = (long long)ws_size - (long long)(10 * BCN);
    long long perb = (long long)N_PIX * N_PIX * 4;           // 4 MiB / batch
    int chunkB = (int)(rem / perb);
    if (chunkB < 1) chunkB = 1;
    if (chunkB > BATCH) chunkB = BATCH;

    gn_kernel<<<BATCH * NGRP, 256, 0, stream>>>(x, gn_w, gn_b, h);
    qkv_kernel<<<dim3(16, 8, 96), 256, 0, stream>>>(h, wq, wk, wv, bq, bk, bv, q, k, v);
    for (int b0 = 0; b0 < BATCH; b0 += chunkB) {
        int cb = (BATCH - b0 < chunkB) ? (BATCH - b0) : chunkB;
        scores_kernel<<<dim3(16, 16, cb), 256, 0, stream>>>(q, k, attn, b0);
        softmax_kernel<<<cb * N_PIX, 256, 0, stream>>>(attn);
        pv_kernel<<<dim3(8, 16, cb), 256, 0, stream>>>(attn, v, O, b0);
    }
    proj_kernel<<<dim3(16, 8, 32), 256, 0, stream>>>(O, wp, bp, x, y);
}

// Round 2
// 498.264 us; speedup vs baseline: 3.8819x; 3.8819x over previous
//
#include <hip/hip_runtime.h>

// AttnBlock B=32, C=512, N=1024. All GEMMs via bf16 MFMA 16x16x32.
// Layouts (all K-contiguous so one GEMM kernel serves everything):
//   h[b][n][c], q[b][n][c], k[b][n][c], v[b][c][n], O[b][n][c]
//   S fp32 [bl][i][j] (chunk of 8 batches, reusing h slot); P bf16 in-place,
//   row stride 2048 u16.
// GEMM: C[m][n] = sum_k A[m][k]*B[n][k]  (A: MxK rm, B: NxK rm)

#define C_DIM 512
#define N_PIX 1024
#define BATCH 32
#define CPG 16
#define EPS 1e-6f
#define SCALE 0.044194173824159216f  // 512^-0.5

typedef unsigned short u16;
typedef __attribute__((ext_vector_type(8))) short bf16x8;
typedef __attribute__((ext_vector_type(4))) float f32x4;

static __device__ __forceinline__ float bf2f(u16 u) {
    union { unsigned int i; float f; } v; v.i = ((unsigned int)u) << 16; return v.f;
}
static __device__ __forceinline__ u16 f2bf(float f) {
    union { float f; unsigned int i; } v; v.f = f;
    unsigned int r = v.i + 0x7fffu + ((v.i >> 16) & 1u);
    return (u16)(r >> 16);
}

static __device__ __forceinline__ void gl_lds16(const u16* g, u16* l) {
    __builtin_amdgcn_global_load_lds(
        (const __attribute__((address_space(1))) unsigned int*)g,
        (__attribute__((address_space(3))) unsigned int*)l,
        16, 0, 0);
}

// ------------------------------------------------------------- weights->bf16
__global__ __launch_bounds__(256) void wconv_kernel(
        const float* __restrict__ wq, const float* __restrict__ wk,
        const float* __restrict__ wv, const float* __restrict__ wp,
        u16* __restrict__ out) {
    int i = blockIdx.x * 256 + threadIdx.x;         // 262144 float4s total
    int mat = i >> 16;
    const float* src = (mat == 0) ? wq : (mat == 1) ? wk : (mat == 2) ? wv : wp;
    float4 v = ((const float4*)src)[i & 65535];
    ushort4 o;
    o.x = f2bf(v.x); o.y = f2bf(v.y); o.z = f2bf(v.z); o.w = f2bf(v.w);
    *(ushort4*)&out[(size_t)i * 4] = o;
}

// ------------------------------------------------------------- GroupNorm
// block = (b,g): 16 ch x 1024 pix. Output h[b][n][c] (transposed via LDS).
__global__ __launch_bounds__(256) void gn_kernel(
        const float* __restrict__ x, const float* __restrict__ gw,
        const float* __restrict__ gb, u16* __restrict__ h) {
    int blk = blockIdx.x;
    int b = blk >> 5, g = blk & 31;
    size_t base = ((size_t)(b * C_DIM + g * CPG)) * N_PIX;
    const float4* xv = (const float4*)(x + base);
    int tid = threadIdx.x;

    float s = 0.f, sq = 0.f;
    for (int i = tid; i < (CPG * N_PIX) / 4; i += 256) {
        float4 v = xv[i];
        s  += v.x + v.y + v.z + v.w;
        sq += v.x * v.x + v.y * v.y + v.z * v.z + v.w * v.w;
    }
    __shared__ float rs[256], rq[256];
    rs[tid] = s; rq[tid] = sq;
    __syncthreads();
    for (int off = 128; off > 0; off >>= 1) {
        if (tid < off) { rs[tid] += rs[tid + off]; rq[tid] += rq[tid + off]; }
        __syncthreads();
    }
    float mean = rs[0] * (1.0f / (CPG * N_PIX));
    float var  = rq[0] * (1.0f / (CPG * N_PIX)) - mean * mean;
    float inv  = rsqrtf(var + EPS);

    __shared__ u16 Ls[CPG * N_PIX];      // 32 KB, [c_local][n]
    for (int i = tid; i < (CPG * N_PIX) / 4; i += 256) {
        int c_local = i >> 8;
        int c = g * CPG + c_local;
        float sc = gw[c] * inv;
        float sh = gb[c] - mean * sc;
        float4 v = xv[i];
        ushort4 o;
        o.x = f2bf(v.x * sc + sh); o.y = f2bf(v.y * sc + sh);
        o.z = f2bf(v.z * sc + sh); o.w = f2bf(v.w * sc + sh);
        *(ushort4*)&Ls[c_local * N_PIX + (i & 255) * 4] = o;
    }
    __syncthreads();
    u16* hb = h + (size_t)b * N_PIX * C_DIM + g * CPG;   // h[b][n][g*16]
    for (int n = tid; n < N_PIX; n += 256) {
        unsigned int pk[8];
#pragma unroll
        for (int j = 0; j < 8; ++j) {
            unsigned int lo = Ls[(2 * j) * N_PIX + n];
            unsigned int hi = Ls[(2 * j + 1) * N_PIX + n];
            pk[j] = lo | (hi << 16);
        }
        uint4* dst = (uint4*)(hb + (size_t)n * C_DIM);
        dst[0] = make_uint4(pk[0], pk[1], pk[2], pk[3]);
        dst[1] = make_uint4(pk[4], pk[5], pk[6], pk[7]);
    }
}

// ------------------------------------------------------------- MFMA GEMM
// MODE 0: bf16 out, +bias[col]   (q,k)
// MODE 1: bf16 out, +bias[row]   (v)
// MODE 2: f32 out, *SCALE        (scores)
// MODE 3: bf16 out, plain        (pv)
// MODE 4: f32 out, +bias[row] + resid  (proj)
// grid: (N/128, M/128, batch). 256 thr = 4 waves (2x2 of 64x64).
template <int MODE>
__global__ __launch_bounds__(256) void gemm_kernel(
        const u16* __restrict__ A, const u16* __restrict__ B,
        void* __restrict__ Cv, const float* __restrict__ bias,
        const float* __restrict__ xres, int K,
        int rsA, int rsB, int rsC,
        long long bsA, long long bsB, long long bsC) {
    int bx = blockIdx.x, by = blockIdx.y, bz = blockIdx.z;
    const u16* gA = A + (size_t)bz * bsA + (size_t)by * 128 * rsA;
    const u16* gB = B + (size_t)bz * bsB + (size_t)bx * 128 * rsB;

    __shared__ __align__(16) u16 As[128 * 64];
    __shared__ __align__(16) u16 Bs[128 * 64];

    int tid = threadIdx.x;
    int lane = tid & 63, wave = tid >> 6;
    int wm = wave >> 1, wn = wave & 1;
    int quad = lane >> 4, l15 = lane & 15, l7 = lane & 7;

    // staging constants: thread t stages 16B granule; i = r*256+t;
    // row m = i>>3, phys granule = i&7, logical = phys ^ (m&7)
    int srow = tid >> 3;                      // 0..31 (base row, +32 per round)
    int lg = (tid & 7) ^ (srow & 7);
    const u16* pA = gA + (size_t)srow * rsA + lg * 8;
    const u16* pB = gB + (size_t)srow * rsB + lg * 8;
    u16* lA = As + tid * 8;
    u16* lB = Bs + tid * 8;

    f32x4 acc[4][4];
#pragma unroll
    for (int mt = 0; mt < 4; ++mt)
#pragma unroll
        for (int nt = 0; nt < 4; ++nt)
            acc[mt][nt] = (f32x4){0.f, 0.f, 0.f, 0.f};

    for (int k0 = 0; k0 < K; k0 += 64) {
#pragma unroll
        for (int r = 0; r < 4; ++r) {
            gl_lds16(pA + (size_t)r * 32 * rsA + k0, lA + r * 2048);
            gl_lds16(pB + (size_t)r * 32 * rsB + k0, lB + r * 2048);
        }
        __syncthreads();
#pragma unroll
        for (int ks = 0; ks < 2; ++ks) {
            bf16x8 af[4], bfr[4];
#pragma unroll
            for (int t = 0; t < 4; ++t) {
                int rA = wm * 64 + t * 16 + l15;
                int gA_ = ((ks * 4 + quad) ^ l7) * 8;
                af[t] = *(const bf16x8*)&As[rA * 64 + gA_];
                int rB = wn * 64 + t * 16 + l15;
                bfr[t] = *(const bf16x8*)&Bs[rB * 64 + gA_];
            }
#pragma unroll
            for (int mt = 0; mt < 4; ++mt)
#pragma unroll
                for (int nt = 0; nt < 4; ++nt)
                    acc[mt][nt] = __builtin_amdgcn_mfma_f32_16x16x32_bf16(
                        af[mt], bfr[nt], acc[mt][nt], 0, 0, 0);
        }
        __syncthreads();
    }

    // epilogue: C/D layout col = lane&15, row = quad*4 + reg
    int colb = bx * 128 + wn * 64 + l15;
    int rowb = by * 128 + wm * 64 + quad * 4;
#pragma unroll
    for (int mt = 0; mt < 4; ++mt) {
#pragma unroll
        for (int nt = 0; nt < 4; ++nt) {
            f32x4 a = acc[mt][nt];
            int gc = colb + nt * 16;
#pragma unroll
            for (int reg = 0; reg < 4; ++reg) {
                int gr = rowb + mt * 16 + reg;
                float val = a[reg];
                size_t idx = (size_t)bz * bsC + (size_t)gr * rsC + gc;
                if (MODE == 0) {
                    ((u16*)Cv)[idx] = f2bf(val + bias[gc]);
                } else if (MODE == 1) {
                    ((u16*)Cv)[idx] = f2bf(val + bias[gr]);
                } else if (MODE == 2) {
                    ((float*)Cv)[idx] = val * SCALE;
                } else if (MODE == 3) {
                    ((u16*)Cv)[idx] = f2bf(val);
                } else {
                    ((float*)Cv)[idx] = val + bias[gr] + xres[idx];
                }
            }
        }
    }
}

// ------------------------------------------------------------- Softmax
// fp32 S row (1024) -> bf16 P written in place (first 2KB of the 4KB row).
__global__ __launch_bounds__(256) void softmax_kernel(float* __restrict__ S) {
    size_t row = blockIdx.x;
    float* p = S + row * N_PIX;
    int tid = threadIdx.x;
    float4 v = ((float4*)p)[tid];
    __shared__ float red[256];
    float m = fmaxf(fmaxf(v.x, v.y), fmaxf(v.z, v.w));
    red[tid] = m; __syncthreads();
    for (int off = 128; off > 0; off >>= 1) {
        if (tid < off) red[tid] = fmaxf(red[tid], red[tid + off]);
        __syncthreads();
    }
    float M = red[0];
    __syncthreads();
    float4 e;
    e.x = __expf(v.x - M); e.y = __expf(v.y - M);
    e.z = __expf(v.z - M); e.w = __expf(v.w - M);
    red[tid] = e.x + e.y + e.z + e.w; __syncthreads();
    for (int off = 128; off > 0; off >>= 1) {
        if (tid < off) red[tid] += red[tid + off];
        __syncthreads();
    }
    float inv = 1.0f / red[0];
    ushort4 st;
    st.x = f2bf(e.x * inv); st.y = f2bf(e.y * inv);
    st.z = f2bf(e.z * inv); st.w = f2bf(e.w * inv);
    *(ushort4*)&((u16*)p)[tid * 4] = st;
}

extern "C" void kernel_launch(void* const* d_in, const int* in_sizes, int n_in,
                              void* d_out, int out_size, void* d_ws, size_t ws_size,
                              hipStream_t stream) {
    const float* x    = (const float*)d_in[0];
    const float* gn_w = (const float*)d_in[1];
    const float* gn_b = (const float*)d_in[2];
    const float* wq   = (const float*)d_in[3];
    const float* bq   = (const float*)d_in[4];
    const float* wk   = (const float*)d_in[5];
    const float* bk   = (const float*)d_in[6];
    const float* wv   = (const float*)d_in[7];
    const float* bv   = (const float*)d_in[8];
    const float* wp   = (const float*)d_in[9];
    const float* bp   = (const float*)d_in[10];
    float* y = (float*)d_out;

    const size_t BCN = (size_t)BATCH * C_DIM * N_PIX;     // 16.78M elems
    char* w = (char*)d_ws;
    u16* h  = (u16*)(w);                                  // 32 MiB (reused as S)
    u16* q  = (u16*)(w + 2 * BCN);
    u16* k  = (u16*)(w + 4 * BCN);
    u16* v  = (u16*)(w + 6 * BCN);
    u16* O  = (u16*)(w + 8 * BCN);
    u16* wb = (u16*)(w + 10 * BCN);                       // 2 MiB bf16 weights
    u16* wqb = wb, *wkb = wb + 262144, *wvb = wb + 524288, *wpb = wb + 786432;
    float* S = (float*)h;                                 // 8-batch score chunk

    const long long BS = 524288;      // per-batch elems for [n][c]/[c][n] bufs

    wconv_kernel<<<1024, 256, 0, stream>>>(wq, wk, wv, wp, wb);
    gn_kernel<<<1024, 256, 0, stream>>>(x, gn_w, gn_b, h);

    // q[n][o] = h[n][c]*wq[o][c] + bq[o]   M=1024 N=512 K=512
    gemm_kernel<0><<<dim3(4, 8, 32), 256, 0, stream>>>(
        h, wqb, q, bq, nullptr, 512, 512, 512, 512, BS, 0, BS);
    gemm_kernel<0><<<dim3(4, 8, 32), 256, 0, stream>>>(
        h, wkb, k, bk, nullptr, 512, 512, 512, 512, BS, 0, BS);
    // v[c][n] = wv[c][c']*h[n][c'] + bv[c]  M=512 N=1024 K=512
    gemm_kernel<1><<<dim3(8, 4, 32), 256, 0, stream>>>(
        wvb, h, v, bv, nullptr, 512, 512, 512, 1024, 0, BS, BS);

    for (int b0 = 0; b0 < BATCH; b0 += 8) {
        // S[i][j] = SCALE * q[i][o]*k[j][o]  M=N=1024 K=512
        gemm_kernel<2><<<dim3(8, 8, 8), 256, 0, stream>>>(
            q + (size_t)b0 * BS, k + (size_t)b0 * BS, S, nullptr, nullptr,
            512, 512, 512, 1024, BS, BS, 1048576LL);
        softmax_kernel<<<8 * 1024, 256, 0, stream>>>(S);
        // O[i][c] = P[i][j]*v[c][j]  M=1024 N=512 K=1024 ; P rows stride 2048
        gemm_kernel<3><<<dim3(4, 8, 8), 256, 0, stream>>>(
            (const u16*)S, v + (size_t)b0 * BS, O + (size_t)b0 * BS,
            nullptr, nullptr, 1024, 2048, 1024, 512, 2097152LL, BS, BS);
    }

    // y[o][n] = x + bp[o] + wp[o][c]*O[n][c]  M=512 N=1024 K=512
    gemm_kernel<4><<<dim3(8, 4, 32), 256, 0, stream>>>(
        wpb, O, y, bp, x, 512, 512, 512, 1024, 0, BS, BS);
}

// Round 3
// 436.776 us; speedup vs baseline: 4.4284x; 1.1408x over previous
//
#include <hip/hip_runtime.h>

// AttnBlock B=32, C=512, N=1024. All GEMMs via bf16 MFMA 16x16x32.
// Layouts: h[b][n][c], q[b][n][c], k[b][n][c], v[b][c][n], O[b][n][c].
// S bf16 [bl][i][j], 16-batch chunks in the dead h slot; P bf16 in place.
// GEMM: C[m][n] = sum_k A[m][k]*B[n][k]  (A: MxK rm, B: NxK rm, K-contig)

#define C_DIM 512
#define N_PIX 1024
#define BATCH 32
#define CPG 16
#define EPS 1e-6f
#define SCALE 0.044194173824159216f  // 512^-0.5
#define ESTRIDE 66                   // epilogue LDS row stride (floats)

typedef unsigned short u16;
typedef __attribute__((ext_vector_type(8))) short bf16x8;
typedef __attribute__((ext_vector_type(4))) float f32x4;
typedef __attribute__((ext_vector_type(2))) float f32x2;

static __device__ __forceinline__ float bf2f(u16 u) {
    union { unsigned int i; float f; } v; v.i = ((unsigned int)u) << 16; return v.f;
}
static __device__ __forceinline__ u16 f2bf(float f) {
    union { float f; unsigned int i; } v; v.f = f;
    unsigned int r = v.i + 0x7fffu + ((v.i >> 16) & 1u);
    return (u16)(r >> 16);
}

static __device__ __forceinline__ void gl_lds16(const u16* g, u16* l) {
    __builtin_amdgcn_global_load_lds(
        (const __attribute__((address_space(1))) unsigned int*)g,
        (__attribute__((address_space(3))) unsigned int*)l,
        16, 0, 0);
}

// ------------------------------------------------------------- weights->bf16
__global__ __launch_bounds__(256) void wconv_kernel(
        const float* __restrict__ wq, const float* __restrict__ wk,
        const float* __restrict__ wv, const float* __restrict__ wp,
        u16* __restrict__ out) {
    int i = blockIdx.x * 256 + threadIdx.x;
    int mat = i >> 16;
    const float* src = (mat == 0) ? wq : (mat == 1) ? wk : (mat == 2) ? wv : wp;
    float4 v = ((const float4*)src)[i & 65535];
    ushort4 o;
    o.x = f2bf(v.x); o.y = f2bf(v.y); o.z = f2bf(v.z); o.w = f2bf(v.w);
    *(ushort4*)&out[(size_t)i * 4] = o;
}

// ------------------------------------------------------------- GroupNorm
__global__ __launch_bounds__(256) void gn_kernel(
        const float* __restrict__ x, const float* __restrict__ gw,
        const float* __restrict__ gb, u16* __restrict__ h) {
    int blk = blockIdx.x;
    int b = blk >> 5, g = blk & 31;
    size_t base = ((size_t)(b * C_DIM + g * CPG)) * N_PIX;
    const float4* xv = (const float4*)(x + base);
    int tid = threadIdx.x;

    float s = 0.f, sq = 0.f;
    for (int i = tid; i < (CPG * N_PIX) / 4; i += 256) {
        float4 v = xv[i];
        s  += v.x + v.y + v.z + v.w;
        sq += v.x * v.x + v.y * v.y + v.z * v.z + v.w * v.w;
    }
    __shared__ float rs[256], rq[256];
    rs[tid] = s; rq[tid] = sq;
    __syncthreads();
    for (int off = 128; off > 0; off >>= 1) {
        if (tid < off) { rs[tid] += rs[tid + off]; rq[tid] += rq[tid + off]; }
        __syncthreads();
    }
    float mean = rs[0] * (1.0f / (CPG * N_PIX));
    float var  = rq[0] * (1.0f / (CPG * N_PIX)) - mean * mean;
    float inv  = rsqrtf(var + EPS);

    __shared__ u16 Ls[CPG * N_PIX];
    for (int i = tid; i < (CPG * N_PIX) / 4; i += 256) {
        int c_local = i >> 8;
        int c = g * CPG + c_local;
        float sc = gw[c] * inv;
        float sh = gb[c] - mean * sc;
        float4 v = xv[i];
        ushort4 o;
        o.x = f2bf(v.x * sc + sh); o.y = f2bf(v.y * sc + sh);
        o.z = f2bf(v.z * sc + sh); o.w = f2bf(v.w * sc + sh);
        *(ushort4*)&Ls[c_local * N_PIX + (i & 255) * 4] = o;
    }
    __syncthreads();
    u16* hb = h + (size_t)b * N_PIX * C_DIM + g * CPG;
    for (int n = tid; n < N_PIX; n += 256) {
        unsigned int pk[8];
#pragma unroll
        for (int j = 0; j < 8; ++j) {
            unsigned int lo = Ls[(2 * j) * N_PIX + n];
            unsigned int hi = Ls[(2 * j + 1) * N_PIX + n];
            pk[j] = lo | (hi << 16);
        }
        uint4* dst = (uint4*)(hb + (size_t)n * C_DIM);
        dst[0] = make_uint4(pk[0], pk[1], pk[2], pk[3]);
        dst[1] = make_uint4(pk[4], pk[5], pk[6], pk[7]);
    }
}

// ------------------------------------------------------------- MFMA GEMM
// MODE 0: q&k (z=mat*32+b), bf16 out +bias[col]
// MODE 1: v, bf16 out +bias[row]
// MODE 2: scores, bf16 out *SCALE
// MODE 3: pv, bf16 out
// MODE 4: proj, f32 out +bias[row]+resid
template <int MODE>
__global__ __launch_bounds__(256) void gemm_kernel(
        const u16* __restrict__ A, const u16* __restrict__ B,
        void* __restrict__ Cv, void* __restrict__ Cv2,
        const float* __restrict__ bias, const float* __restrict__ bias2,
        const float* __restrict__ xres, int K,
        int rsA, int rsB, int rsC,
        long long bsA, long long bsB, long long bsC) {
    int bx = blockIdx.x, by = blockIdx.y, bz = blockIdx.z;
    int mat = 0, b = bz;
    if (MODE == 0) { mat = bz >> 5; b = bz & 31; }
    const u16* gA = A + (size_t)b * bsA + (size_t)by * 128 * rsA;
    const u16* gB;
    if (MODE == 0) gB = B + (size_t)mat * 262144 + (size_t)bx * 128 * rsB;
    else           gB = B + (size_t)b * bsB + (size_t)bx * 128 * rsB;
    void* out = (MODE == 0 && mat) ? Cv2 : Cv;
    const float* bi_p = (MODE == 0 && mat) ? bias2 : bias;

    __shared__ __align__(16) u16 smem[16384];     // 32 KB
    u16* As = smem;
    u16* Bs = smem + 8192;

    int tid = threadIdx.x;
    int lane = tid & 63, wave = tid >> 6;
    int wm = wave >> 1, wn = wave & 1;
    int quad = lane >> 4, l15 = lane & 15, l7 = lane & 7;

    int srow = tid >> 3;
    int lg = (tid & 7) ^ (srow & 7);
    const u16* pA = gA + (size_t)srow * rsA + lg * 8;
    const u16* pB = gB + (size_t)srow * rsB + lg * 8;
    u16* lA = As + tid * 8;
    u16* lB = Bs + tid * 8;

    f32x4 acc[4][4];
#pragma unroll
    for (int mt = 0; mt < 4; ++mt)
#pragma unroll
        for (int nt = 0; nt < 4; ++nt)
            acc[mt][nt] = (f32x4){0.f, 0.f, 0.f, 0.f};

    for (int k0 = 0; k0 < K; k0 += 64) {
#pragma unroll
        for (int r = 0; r < 4; ++r) {
            gl_lds16(pA + (size_t)r * 32 * rsA + k0, lA + r * 2048);
            gl_lds16(pB + (size_t)r * 32 * rsB + k0, lB + r * 2048);
        }
        __syncthreads();
#pragma unroll
        for (int ks = 0; ks < 2; ++ks) {
            bf16x8 af[4], bfr[4];
#pragma unroll
            for (int t = 0; t < 4; ++t) {
                int rA = wm * 64 + t * 16 + l15;
                int gr_ = ((ks * 4 + quad) ^ l7) * 8;
                af[t] = *(const bf16x8*)&As[rA * 64 + gr_];
                int rB = wn * 64 + t * 16 + l15;
                bfr[t] = *(const bf16x8*)&Bs[rB * 64 + gr_];
            }
#pragma unroll
            for (int mt = 0; mt < 4; ++mt)
#pragma unroll
                for (int nt = 0; nt < 4; ++nt)
                    acc[mt][nt] = __builtin_amdgcn_mfma_f32_16x16x32_bf16(
                        af[mt], bfr[nt], acc[mt][nt], 0, 0, 0);
        }
        __syncthreads();
    }

    // epilogue: per-wave LDS transpose, then vectorized global stores.
    // C/D frag: col = l15 (+nt*16), row = quad*4+reg (+mt*16).
    float* ebw = (float*)smem + wave * (16 * ESTRIDE);
    int er = lane >> 4;             // read row group 0..3
    int ec4 = (lane & 15) * 4;      // read col 0,4,..60
    int colb = bx * 128 + wn * 64;
    int rowb = by * 128 + wm * 64;
#pragma unroll
    for (int mt = 0; mt < 4; ++mt) {
#pragma unroll
        for (int nt = 0; nt < 4; ++nt) {
            f32x4 a = acc[mt][nt];
#pragma unroll
            for (int reg = 0; reg < 4; ++reg)
                ebw[(quad * 4 + reg) * ESTRIDE + nt * 16 + l15] = a[reg];
        }
        // wave-private region: in-order LDS within a wave, no barrier needed
#pragma unroll
        for (int j = 0; j < 4; ++j) {
            int lr = er + 4 * j;
            f32x2 v0 = *(f32x2*)&ebw[lr * ESTRIDE + ec4];
            f32x2 v1 = *(f32x2*)&ebw[lr * ESTRIDE + ec4 + 2];
            int gr = rowb + mt * 16 + lr;
            int gc = colb + ec4;
            size_t cidx = (size_t)b * bsC + (size_t)gr * rsC + gc;
            if (MODE == 0) {
                float4 b4 = *(const float4*)&bi_p[gc];
                ushort4 st;
                st.x = f2bf(v0.x + b4.x); st.y = f2bf(v0.y + b4.y);
                st.z = f2bf(v1.x + b4.z); st.w = f2bf(v1.y + b4.w);
                *(ushort4*)&((u16*)out)[cidx] = st;
            } else if (MODE == 1) {
                float bi = bi_p[gr];
                ushort4 st;
                st.x = f2bf(v0.x + bi); st.y = f2bf(v0.y + bi);
                st.z = f2bf(v1.x + bi); st.w = f2bf(v1.y + bi);
                *(ushort4*)&((u16*)out)[cidx] = st;
            } else if (MODE == 2) {
                ushort4 st;
                st.x = f2bf(v0.x * SCALE); st.y = f2bf(v0.y * SCALE);
                st.z = f2bf(v1.x * SCALE); st.w = f2bf(v1.y * SCALE);
                *(ushort4*)&((u16*)out)[cidx] = st;
            } else if (MODE == 3) {
                ushort4 st;
                st.x = f2bf(v0.x); st.y = f2bf(v0.y);
                st.z = f2bf(v1.x); st.w = f2bf(v1.y);
                *(ushort4*)&((u16*)out)[cidx] = st;
            } else {
                float bi = bi_p[gr];
                float4 xr = *(const float4*)&xres[cidx];
                float4 st = make_float4(v0.x + bi + xr.x, v0.y + bi + xr.y,
                                        v1.x + bi + xr.z, v1.y + bi + xr.w);
                *(float4*)&((float*)out)[cidx] = st;
            }
        }
    }
}

// ------------------------------------------------------------- Softmax
// bf16 S row (1024) -> bf16 P in place.
__global__ __launch_bounds__(256) void softmax_kernel(u16* __restrict__ S) {
    size_t row = blockIdx.x;
    u16* p = S + row * N_PIX;
    int tid = threadIdx.x;
    ushort4 uv = *(ushort4*)&p[tid * 4];
    float4 v = make_float4(bf2f(uv.x), bf2f(uv.y), bf2f(uv.z), bf2f(uv.w));
    __shared__ float red[256];
    float m = fmaxf(fmaxf(v.x, v.y), fmaxf(v.z, v.w));
    red[tid] = m; __syncthreads();
    for (int off = 128; off > 0; off >>= 1) {
        if (tid < off) red[tid] = fmaxf(red[tid], red[tid + off]);
        __syncthreads();
    }
    float M = red[0];
    __syncthreads();
    float4 e;
    e.x = __expf(v.x - M); e.y = __expf(v.y - M);
    e.z = __expf(v.z - M); e.w = __expf(v.w - M);
    red[tid] = e.x + e.y + e.z + e.w; __syncthreads();
    for (int off = 128; off > 0; off >>= 1) {
        if (tid < off) red[tid] += red[tid + off];
        __syncthreads();
    }
    float inv = 1.0f / red[0];
    ushort4 st;
    st.x = f2bf(e.x * inv); st.y = f2bf(e.y * inv);
    st.z = f2bf(e.z * inv); st.w = f2bf(e.w * inv);
    *(ushort4*)&p[tid * 4] = st;
}

extern "C" void kernel_launch(void* const* d_in, const int* in_sizes, int n_in,
                              void* d_out, int out_size, void* d_ws, size_t ws_size,
                              hipStream_t stream) {
    const float* x    = (const float*)d_in[0];
    const float* gn_w = (const float*)d_in[1];
    const float* gn_b = (const float*)d_in[2];
    const float* wq   = (const float*)d_in[3];
    const float* bq   = (const float*)d_in[4];
    const float* wk   = (const float*)d_in[5];
    const float* bk   = (const float*)d_in[6];
    const float* wv   = (const float*)d_in[7];
    const float* bv   = (const float*)d_in[8];
    const float* wp   = (const float*)d_in[9];
    const float* bp   = (const float*)d_in[10];
    float* y = (float*)d_out;

    const size_t BCN = (size_t)BATCH * C_DIM * N_PIX;
    char* w = (char*)d_ws;
    u16* h  = (u16*)(w);                       // 33.5 MB; reused as S (16b chunk)
    u16* q  = (u16*)(w + 2 * BCN);
    u16* k  = (u16*)(w + 4 * BCN);
    u16* v  = (u16*)(w + 6 * BCN);
    u16* O  = (u16*)(w + 8 * BCN);
    u16* wb = (u16*)(w + 10 * BCN);            // 2 MB bf16 weights
    u16* wvb = wb + 524288, *wpb = wb + 786432;
    u16* S = h;

    const long long BS = 524288;               // per-batch elems
    const long long SB = 1048576;              // per-batch S elems

    wconv_kernel<<<1024, 256, 0, stream>>>(wq, wk, wv, wp, wb);
    gn_kernel<<<1024, 256, 0, stream>>>(x, gn_w, gn_b, h);

    // q,k[n][o] = h[n][c]*w[o][c] + b[o]   M=1024 N=512 K=512, z=mat*32+b
    gemm_kernel<0><<<dim3(4, 8, 64), 256, 0, stream>>>(
        h, wb, q, k, bq, bk, nullptr, 512, 512, 512, 512, BS, 0, BS);
    // v[c][n] = wv[c][c']*h[n][c'] + bv[c]  M=512 N=1024 K=512
    gemm_kernel<1><<<dim3(8, 4, 32), 256, 0, stream>>>(
        wvb, h, v, nullptr, bv, nullptr, nullptr, 512, 512, 512, 1024, 0, BS, BS);

    for (int b0 = 0; b0 < BATCH; b0 += 16) {
        // S[i][j] = SCALE * q[i][o]*k[j][o]  (bf16 out) M=N=1024 K=512
        gemm_kernel<2><<<dim3(8, 8, 16), 256, 0, stream>>>(
            q + (size_t)b0 * BS, k + (size_t)b0 * BS, S, nullptr,
            nullptr, nullptr, nullptr, 512, 512, 512, 1024, BS, BS, SB);
        softmax_kernel<<<16 * 1024, 256, 0, stream>>>(S);
        // O[i][c] = P[i][j]*v[c][j]  M=1024 N=512 K=1024
        gemm_kernel<3><<<dim3(4, 8, 16), 256, 0, stream>>>(
            S, v + (size_t)b0 * BS, O + (size_t)b0 * BS, nullptr,
            nullptr, nullptr, nullptr, 1024, 1024, 1024, 512, SB, BS, BS);
    }

    // y[o][n] = x + bp[o] + wp[o][c]*O[n][c]  M=512 N=1024 K=512
    gemm_kernel<4><<<dim3(8, 4, 32), 256, 0, stream>>>(
        wpb, O, y, nullptr, bp, nullptr, x, 512, 512, 512, 1024, 0, BS, BS);
}